// Round 4
// baseline (240.976 us; speedup 1.0000x reference)
//
#include <hip/hip_runtime.h>

#define NPG 64
#define IN 16
#define DM 128
#define NOUT 64
#define EPG 4096
#define BN_EPS 1e-5f

// ---------------------------------------------------------------------------
// ws layout:
//   u32 arr[256] stride-16 @ u32 ofs 0      (16 KB)  - per-block epoch lines
//   v0acc @ ws+4096  (16384 floats, 64 KB)  - atomically accumulated layer-0
//   v1    @ ws+20480 (16384 floats)
//   v2    @ ws+36864 (16384 floats)
// First 81920 bytes (arr + v0acc) memset to 0 each launch.
//
// One-hop all-observe barrier: each block's t0 stores epoch to its own line
// (after __threadfence releasing its plain stores / atomics); EVERY thread of
// EVERY block polls one line (load-only, agent scope, s_sleep backoff). No
// RMW storm (round-1 lesson), no releaser hop (round-3 lesson). Profiler
// replays without the memset see epoch>=e and fall through (no hang).
// ---------------------------------------------------------------------------
__device__ __forceinline__ void obar(unsigned* arr, unsigned e, int bid, int t) {
    __syncthreads();
    if (t == 0) {
        __threadfence();                                    // release
        __hip_atomic_store(&arr[bid * 16], e,
                           __ATOMIC_RELAXED, __HIP_MEMORY_SCOPE_AGENT);
    }
    while (__hip_atomic_load(&arr[t * 16],
                             __ATOMIC_RELAXED, __HIP_MEMORY_SCOPE_AGENT) < e)
        __builtin_amdgcn_s_sleep(2);
    __threadfence();                                        // acquire
    __syncthreads();
}

// ---------------------------------------------------------------------------
// MLP layer with REDUNDANT batch-norm stats: every block reads the full
// [128g x 128f] input table (64 KB, coalesced, IC-resident), computes
// mean/var itself -> no stats barrier. Block = (f = bid&127, gh = bid>>7).
// relu applied at read (idempotent for post-relu inputs).
// ---------------------------------------------------------------------------
__device__ void mlp_phase2(float* u,
    const float* __restrict__ vin,
    const float* __restrict__ gbn, const float* __restrict__ bbn,
    const float* __restrict__ W, const float* __restrict__ bias,
    float* __restrict__ vout)
{
    float* vraw = u;            // 64*129 = 8256 (own-half graphs)
    float* sc   = u + 8256;     // 128
    float* sh   = u + 8384;     // 128
    float* wcol = u + 8512;     // 128
    float* pc   = u + 8640;     // 256
    float* s1h  = u + 8896;     // 256
    float* s2h  = u + 9152;     // 256
    const int b = blockIdx.x, t = threadIdx.x;
    const int f = b & 127, gh = b >> 7;
    const int fc = t & 127, half = t >> 7;
    if (t < 128) wcol[t] = W[t * 128 + f];
    // redundant stats: thread (fc,half) sums its column over 64 graphs;
    // per-wave reads are 256B contiguous (coalesced).
    float s1 = 0.f, s2 = 0.f;
    const int gbase = half * 64;
    #pragma unroll 4
    for (int g = 0; g < 64; g++) {
        float v = fmaxf(vin[(size_t)(gbase + g) * 128 + fc], 0.f);
        s1 += v; s2 += v * v;
        if (half == gh) vraw[g * 129 + fc] = v;   // stash own-half graphs
    }
    s1h[t] = s1; s2h[t] = s2;
    __syncthreads();
    if (t < 128) {
        float S1 = s1h[t] + s1h[t + 128];
        float S2 = s2h[t] + s2h[t + 128];
        float m = S1 * (1.f / 128.f);
        float var = S2 * (1.f / 128.f) - m * m;
        float scv = gbn[t] * rsqrtf(var + BN_EPS);
        sc[t] = scv; sh[t] = bbn[t] - m * scv;
    }
    __syncthreads();
    #pragma unroll
    for (int e = t; e < 8192; e += 256) {        // apply BN in place
        int g = e >> 7, k = e & 127;
        vraw[g * 129 + k] = vraw[g * 129 + k] * sc[k] + sh[k];
    }
    __syncthreads();
    {
        const int gl = t & 63, kh = t >> 6;
        float acc = 0.f;
        #pragma unroll 8
        for (int k = kh * 32; k < kh * 32 + 32; ++k)
            acc += vraw[gl * 129 + k] * wcol[k];
        pc[gl * 4 + kh] = acc;
    }
    __syncthreads();
    if (t < 64) {
        float v = fmaxf(pc[t * 4] + pc[t * 4 + 1] + pc[t * 4 + 2] + pc[t * 4 + 3]
                        + bias[f], 0.f);
        vout[(size_t)(gh * 64 + t) * 128 + f] = v;   // post-relu
    }
}

// ---------------------------------------------------------------------------
// Fused: F (conv 128 blks + gemm 64 blks K=160, atomic-accum into v0acc)
// |bar| M1' |bar| M2' |bar(exit>=128)| O (128 blks). 3 grid barriers total.
// ---------------------------------------------------------------------------
__global__ __launch_bounds__(256) void k_fused(
    const float* __restrict__ x, const float* __restrict__ ew,
    const float* __restrict__ W1, const float* __restrict__ b1,
    const float* __restrict__ W2, const float* __restrict__ b2,
    const float* __restrict__ Wm0, const float* __restrict__ bm0,
    const float* __restrict__ gbn0, const float* __restrict__ bbn0,
    const float* __restrict__ Wm1, const float* __restrict__ bm1,
    const float* __restrict__ gbn1, const float* __restrict__ bbn1,
    const float* __restrict__ Wm2, const float* __restrict__ bm2,
    const float* __restrict__ gbn2, const float* __restrict__ bbn2,
    const float* __restrict__ Wo, const float* __restrict__ bo,
    float* __restrict__ ws, float* __restrict__ out)
{
    __shared__ __align__(16) float u[16128];   // 63KB union, reused per phase
    unsigned* arr = (unsigned*)ws;             // 256 x stride16 epoch lines
    float* v0acc = ws + 4096;                  // 16384
    float* v1    = ws + 20480;                 // 16384
    float* v2    = ws + 36864;                 // 16384
    const int bid = blockIdx.x, t = threadIdx.x;

    // ======================= phase F =======================
    if (bid < 128) {
        // ---------------- conv path (one block per graph) ----------------
        float* ew_s     = u;             // [i][j] 4096 (raw)
        float* x_s      = u + 4096;      // x^T [k][i] 1024
        float* W1_s     = u + 5120;      // [k][f] 2048
        float* P_s      = u + 7168;      // [i][f] 8192 (dinv_i * P)
        float* b1_s     = u + 15360;     // 128
        float* dinv_s   = u + 15488;     // 64
        float* t_s      = u + 15552;     // 64
        float* zp       = u + 4096;      // overlay (x_s/W1_s dead): 16*132
        float* z_full   = u + 15616;     // 128
        float* pooled_s = u + 15744;     // 128
        float* pp2      = u + 15872;     // 256
        const int g = bid;
        {
            const float4* ew4 = (const float4*)(ew + g * EPG);
            float4* ews4 = (float4*)ew_s;
            #pragma unroll
            for (int i = 0; i < 4; i++) ews4[t + 256 * i] = ew4[t + 256 * i];
            const int xi = t & 63, k4 = (t >> 6) * 4;
            float4 xv = *(const float4*)(x + g * NPG * IN + xi * IN + k4);
            x_s[(k4 + 0) * 64 + xi] = xv.x;
            x_s[(k4 + 1) * 64 + xi] = xv.y;
            x_s[(k4 + 2) * 64 + xi] = xv.z;
            x_s[(k4 + 3) * 64 + xi] = xv.w;
            ((float4*)W1_s)[t]       = ((const float4*)W1)[t];
            ((float4*)W1_s)[t + 256] = ((const float4*)W1)[t + 256];
            if (t < 128) b1_s[t] = b1[t];
        }
        __syncthreads();

        if (t < NPG) {
            float s = 0.f;
            #pragma unroll 8
            for (int i = 0; i < NPG; i++) s += ew_s[i * NPG + t];
            dinv_s[t] = (s > 0.f) ? rsqrtf(s) : 0.f;
        }
        __syncthreads();

        {   // t_s[i] = dinv_i * (sum_j ew[i,j] dinv_j) / 64
            const int j = t & 63, q = t >> 6;
            const float dj = dinv_s[j];
            for (int i = q * 16; i < q * 16 + 16; i++) {
                float vv = ew_s[i * NPG + j] * dj;
                #pragma unroll
                for (int off = 32; off > 0; off >>= 1) vv += __shfl_down(vv, off, 64);
                if (j == 0) t_s[i] = dinv_s[i] * vv * (1.f / 64.f);
            }
        }

        {   // P' = dinv_i * (x @ W1)
            const int it = t & 15, ft = t >> 4;
            const int i0 = it * 4, f0 = ft * 8;
            float accp[4][8];
            #pragma unroll
            for (int a = 0; a < 4; a++)
                #pragma unroll
                for (int c = 0; c < 8; c++) accp[a][c] = 0.f;
            #pragma unroll
            for (int k = 0; k < IN; k++) {
                const float4 a4  = *(const float4*)(x_s + k * 64 + i0);
                const float4 b0v = *(const float4*)(W1_s + k * DM + f0);
                const float4 b1v = *(const float4*)(W1_s + k * DM + f0 + 4);
                const float av[4] = {a4.x, a4.y, a4.z, a4.w};
                const float bv[8] = {b0v.x, b0v.y, b0v.z, b0v.w, b1v.x, b1v.y, b1v.z, b1v.w};
                #pragma unroll
                for (int a = 0; a < 4; a++)
                    #pragma unroll
                    for (int c = 0; c < 8; c++) accp[a][c] += av[a] * bv[c];
            }
            #pragma unroll
            for (int a = 0; a < 4; a++) {
                const float di = dinv_s[i0 + a];
                float4* o = (float4*)(P_s + (i0 + a) * DM + f0);
                o[0] = make_float4(di * accp[a][0], di * accp[a][1],
                                   di * accp[a][2], di * accp[a][3]);
                o[1] = make_float4(di * accp[a][4], di * accp[a][5],
                                   di * accp[a][6], di * accp[a][7]);
            }
        }
        __syncthreads();

        {   // aggregation + z-partials
            const int jt = t & 15, ft = t >> 4;
            const int j0 = jt * 4, f0 = ft * 8;
            float acc[4][8];
            #pragma unroll
            for (int a = 0; a < 4; a++)
                #pragma unroll
                for (int c = 0; c < 8; c++) acc[a][c] = 0.f;
            #pragma unroll 4
            for (int k = 0; k < 64; k++) {
                const float4 a4  = *(const float4*)(ew_s + k * 64 + j0);
                const float4 b0v = *(const float4*)(P_s + k * DM + f0);
                const float4 b1v = *(const float4*)(P_s + k * DM + f0 + 4);
                const float av[4] = {a4.x, a4.y, a4.z, a4.w};
                const float bv[8] = {b0v.x, b0v.y, b0v.z, b0v.w, b1v.x, b1v.y, b1v.z, b1v.w};
                #pragma unroll
                for (int a = 0; a < 4; a++)
                    #pragma unroll
                    for (int c = 0; c < 8; c++) acc[a][c] += av[a] * bv[c];
            }
            float zpart[8];
            #pragma unroll
            for (int c = 0; c < 8; c++) zpart[c] = 0.f;
            #pragma unroll
            for (int a = 0; a < 4; a++) {
                const float dj = dinv_s[j0 + a], tj = t_s[j0 + a];
                #pragma unroll
                for (int c = 0; c < 8; c++) {
                    float h = fmaxf(dj * acc[a][c] + b1_s[f0 + c], 0.f);
                    zpart[c] += tj * h;
                }
            }
            float4* zo = (float4*)(zp + jt * 132 + f0);
            zo[0] = make_float4(zpart[0], zpart[1], zpart[2], zpart[3]);
            zo[1] = make_float4(zpart[4], zpart[5], zpart[6], zpart[7]);
        }
        __syncthreads();

        if (t < 128) {
            float s = 0.f;
            #pragma unroll
            for (int jt = 0; jt < 16; jt++) s += zp[jt * 132 + t];
            z_full[t] = s;
        }
        __syncthreads();

        {   // pooled = relu(z @ W2 + b2)
            const int c = t & 127, kh = t >> 7;
            float acc = 0.f;
            #pragma unroll 8
            for (int k = kh * 64; k < kh * 64 + 64; k++)
                acc += z_full[k] * W2[k * DM + c];
            pp2[kh * 128 + c] = acc;
        }
        __syncthreads();
        if (t < 128) pooled_s[t] = fmaxf(pp2[t] + pp2[128 + t] + b2[t], 0.f);
        __syncthreads();

        {   // ppart = pooled @ Wm0[0:128,:]
            const int f = t & 127, kh = t >> 7;
            float acc = 0.f;
            #pragma unroll 8
            for (int k = kh * 64; k < kh * 64 + 64; k++)
                acc += pooled_s[k] * Wm0[k * DM + f];
            pp2[kh * 128 + f] = acc;
        }
        __syncthreads();
        // contribute pooled-part + bm0 directly into v0acc
        if (t < 128) atomicAdd(&v0acc[g * DM + t], pp2[t] + pp2[128 + t] + bm0[t]);
    } else if (bid < 192) {
        // -------- gemm x/ew path: 64 blocks, K=160 (2 staging passes) --------
        const int c = bid - 128;
        const int kc = c >> 1, fh = c & 1;
        float* a_s = u;                  // [k][g] 80*132
        float* b_s = u + 10560;          // [k][fl] 80*64

        const int gthr = t & 31, fthr = t >> 5;   // 32 x 8
        const int g0 = gthr * 4, f0 = fthr * 8;
        float acc[4][8];
        #pragma unroll
        for (int i = 0; i < 4; i++)
            #pragma unroll
            for (int jx = 0; jx < 8; jx++) acc[i][jx] = 0.f;

        for (int pass = 0; pass < 2; pass++) {
            const int K0 = kc * 160 + pass * 80;
            float4 va[8], vb2[2], vc[5];
            #pragma unroll
            for (int it = 0; it < 8; it++) {             // k 0..63: 2048 float4
                int idx = it * 256 + t;
                int gg = idx >> 4, k4 = (idx & 15) << 2;
                int K = K0 + k4;
                const float* src = (K < 1024) ? (x + gg * 1024 + K)
                                              : (ew + gg * 4096 + (K - 1024));
                va[it] = *(const float4*)src;
            }
            #pragma unroll
            for (int it = 0; it < 2; it++) {             // k 64..79: 512 float4
                int idx = it * 256 + t;
                int gg = idx >> 2, k4 = 64 + ((idx & 3) << 2);
                int K = K0 + k4;
                const float* src = (K < 1024) ? (x + gg * 1024 + K)
                                              : (ew + gg * 4096 + (K - 1024));
                vb2[it] = *(const float4*)src;
            }
            #pragma unroll
            for (int it = 0; it < 5; it++) {             // Wm0 slice: 1280 float4
                int idx = it * 256 + t;
                int k = idx >> 4, fl4 = (idx & 15) << 2;
                vc[it] = *(const float4*)(Wm0 + (size_t)(128 + K0 + k) * 128
                                          + fh * 64 + fl4);
            }
            #pragma unroll
            for (int it = 0; it < 8; it++) {
                int idx = it * 256 + t;
                int gg = idx >> 4, k4 = (idx & 15) << 2;
                a_s[(k4 + 0) * 132 + gg] = fmaxf(va[it].x, 0.f);
                a_s[(k4 + 1) * 132 + gg] = fmaxf(va[it].y, 0.f);
                a_s[(k4 + 2) * 132 + gg] = fmaxf(va[it].z, 0.f);
                a_s[(k4 + 3) * 132 + gg] = fmaxf(va[it].w, 0.f);
            }
            #pragma unroll
            for (int it = 0; it < 2; it++) {
                int idx = it * 256 + t;
                int gg = idx >> 2, k4 = 64 + ((idx & 3) << 2);
                a_s[(k4 + 0) * 132 + gg] = fmaxf(vb2[it].x, 0.f);
                a_s[(k4 + 1) * 132 + gg] = fmaxf(vb2[it].y, 0.f);
                a_s[(k4 + 2) * 132 + gg] = fmaxf(vb2[it].z, 0.f);
                a_s[(k4 + 3) * 132 + gg] = fmaxf(vb2[it].w, 0.f);
            }
            #pragma unroll
            for (int it = 0; it < 5; it++) {
                int idx = it * 256 + t;
                int k = idx >> 4, fl4 = (idx & 15) << 2;
                *(float4*)(b_s + k * 64 + fl4) = vc[it];
            }
            __syncthreads();

            #pragma unroll 4
            for (int k = 0; k < 80; k++) {
                const float4 a4  = *(const float4*)(a_s + k * 132 + g0);
                const float4 c0v = *(const float4*)(b_s + k * 64 + f0);
                const float4 c1v = *(const float4*)(b_s + k * 64 + f0 + 4);
                const float av[4] = {a4.x, a4.y, a4.z, a4.w};
                const float bv[8] = {c0v.x, c0v.y, c0v.z, c0v.w, c1v.x, c1v.y, c1v.z, c1v.w};
                #pragma unroll
                for (int i = 0; i < 4; i++)
                    #pragma unroll
                    for (int jx = 0; jx < 8; jx++) acc[i][jx] += av[i] * bv[jx];
            }
            __syncthreads();   // before restage of pass 1
        }

        // accumulate into v0acc (device-scope f32 atomics; ~8192/block)
        #pragma unroll
        for (int i = 0; i < 4; i++)
            #pragma unroll
            for (int jx = 0; jx < 8; jx++)
                atomicAdd(&v0acc[(size_t)(g0 + i) * 128 + fh * 64 + f0 + jx],
                          acc[i][jx]);
    }
    // blocks 192..255 idle in F, arrive immediately
    obar(arr, 1u, bid, t);

    // ============== M1', M2' (redundant-stats, no stats barrier) ==============
    mlp_phase2(u, v0acc, gbn0, bbn0, Wm1, bm1, v1);
    obar(arr, 2u, bid, t);
    mlp_phase2(u, v1, gbn1, bbn1, Wm2, bm2, v2);

    // barrier 3: all arrive; blocks >=128 exit after arrival
    __syncthreads();
    if (t == 0) {
        __threadfence();
        __hip_atomic_store(&arr[bid * 16], 3u,
                           __ATOMIC_RELAXED, __HIP_MEMORY_SCOPE_AGENT);
    }
    if (bid >= 128) return;
    while (__hip_atomic_load(&arr[t * 16],
                             __ATOMIC_RELAXED, __HIP_MEMORY_SCOPE_AGENT) < 3u)
        __builtin_amdgcn_s_sleep(2);
    __threadfence();
    __syncthreads();

    // ============ phase O: redundant BN2 stats + output (1 graph/blk) ============
    {
        float* Wo_s = u;            // 8192 (32KB)
        float* vrow = u + 8192;     // 128
        float* sc   = u + 8320;     // 128
        float* sh   = u + 8448;     // 128
        float* pc   = u + 8576;     // 256
        float* s1h  = u + 8832;     // 256
        float* s2h  = u + 9088;     // 256
        const int g = bid;
        {   // stage Wo 128x64 (2048 float4)
            const float4* wo4 = (const float4*)Wo;
            float4* wos4 = (float4*)Wo_s;
            #pragma unroll
            for (int it = 0; it < 8; it++) wos4[it * 256 + t] = wo4[it * 256 + t];
        }
        // redundant stats over v2 (post-relu already)
        const int fc = t & 127, half = t >> 7;
        float s1 = 0.f, s2 = 0.f;
        const int gbase = half * 64;
        #pragma unroll 4
        for (int gg = 0; gg < 64; gg++) {
            float v = v2[(size_t)(gbase + gg) * 128 + fc];
            s1 += v; s2 += v * v;
        }
        s1h[t] = s1; s2h[t] = s2;
        __syncthreads();
        if (t < 128) {
            float S1 = s1h[t] + s1h[t + 128];
            float S2 = s2h[t] + s2h[t + 128];
            float m = S1 * (1.f / 128.f);
            float var = S2 * (1.f / 128.f) - m * m;
            float scv = gbn2[t] * rsqrtf(var + BN_EPS);
            sc[t] = scv; sh[t] = bbn2[t] - m * scv;
        }
        __syncthreads();
        if (t < 32) {
            float4 vv = ((const float4*)(v2 + g * 128))[t];
            const int k4 = t * 4;
            vrow[k4 + 0] = vv.x * sc[k4 + 0] + sh[k4 + 0];
            vrow[k4 + 1] = vv.y * sc[k4 + 1] + sh[k4 + 1];
            vrow[k4 + 2] = vv.z * sc[k4 + 2] + sh[k4 + 2];
            vrow[k4 + 3] = vv.w * sc[k4 + 3] + sh[k4 + 3];
        }
        __syncthreads();
        {   // 64 o-cols x 4 k-quarters
            const int o = t & 63, kh = t >> 6;
            float acc = 0.f;
            #pragma unroll 8
            for (int k = kh * 32; k < kh * 32 + 32; k++)
                acc += vrow[k] * Wo_s[k * 64 + o];
            pc[kh * 64 + o] = acc;
        }
        __syncthreads();
        if (t < 64)
            out[g * NOUT + t] = pc[t] + pc[64 + t] + pc[128 + t] + pc[192 + t] + bo[t];
    }
}

extern "C" void kernel_launch(void* const* d_in, const int* in_sizes, int n_in,
                              void* d_out, int out_size, void* d_ws, size_t ws_size,
                              hipStream_t stream)
{
    const float* x   = (const float*)d_in[0];
    const float* ew  = (const float*)d_in[2];
    const float* W1  = (const float*)d_in[4];
    const float* b1  = (const float*)d_in[5];
    const float* W2  = (const float*)d_in[6];
    const float* b2  = (const float*)d_in[7];
    const float* Wm0 = (const float*)d_in[8];
    const float* bm0 = (const float*)d_in[9];
    const float* g0  = (const float*)d_in[10];
    const float* be0 = (const float*)d_in[11];
    const float* Wm1 = (const float*)d_in[12];
    const float* bm1 = (const float*)d_in[13];
    const float* g1  = (const float*)d_in[14];
    const float* be1 = (const float*)d_in[15];
    const float* Wm2 = (const float*)d_in[16];
    const float* bm2 = (const float*)d_in[17];
    const float* g2  = (const float*)d_in[18];
    const float* be2 = (const float*)d_in[19];
    const float* Wo  = (const float*)d_in[20];
    const float* bo  = (const float*)d_in[21];

    float* ws = (float*)d_ws;
    // zero epoch lines (16 KB) + v0acc accumulator (64 KB)
    hipMemsetAsync(d_ws, 0, 81920, stream);
    k_fused<<<256, 256, 0, stream>>>(x, ew, W1, b1, W2, b2,
                                     Wm0, bm0, g0, be0,
                                     Wm1, bm1, g1, be1,
                                     Wm2, bm2, g2, be2,
                                     Wo, bo, ws, (float*)d_out);
}

// Round 5
// 151.104 us; speedup vs baseline: 1.5948x; 1.5948x over previous
//
#include <hip/hip_runtime.h>

#define NPG 64
#define IN 16
#define DM 128
#define NOUT 64
#define EPG 4096
#define BN_EPS 1e-5f

// ---------------------------------------------------------------------------
// Coherence strategy: ALL cross-phase data uses agent-scope relaxed atomic
// stores/loads (sc1 write-through -> Infinity Cache). No dirty L2 lines to
// flush => grid barriers need NO __threadfence (no buffer_wbl2 L2-wide
// writeback, the suspected ~12us/barrier cost of rounds 1-4).
// ---------------------------------------------------------------------------
__device__ __forceinline__ void stg(float* p, float v) {
    __hip_atomic_store(p, v, __ATOMIC_RELAXED, __HIP_MEMORY_SCOPE_AGENT);
}
__device__ __forceinline__ float lda(const float* p) {
    return __hip_atomic_load(p, __ATOMIC_RELAXED, __HIP_MEMORY_SCOPE_AGENT);
}

// ---------------------------------------------------------------------------
// Fence-free grid barrier. ctrl u32 layout (memset 0 each launch):
//   epoch e in 1..4: sub[8] @ e*160 + sg*16, root @ e*160+128
//   flags[256] stride16 @ 1024
// __syncthreads drains each wave's outstanding (sc1) stores before arrival.
// Arrival: spread-line RMWs (8x32 + 1x8, round-1 lesson). Release: root
// thread stores 256 private lines; t0-only polls own line (round-4 lesson).
// Profiler replays without memset see flags>=e and fall through (no hang).
// ---------------------------------------------------------------------------
__device__ __forceinline__ void gbar(unsigned* bu, unsigned e, int bid, int t,
                                     bool wait) {
    __syncthreads();
    if (t == 0) {
        unsigned* sub   = bu + e * 160 + (bid & 7) * 16;
        unsigned* root  = bu + e * 160 + 128;
        unsigned* flags = bu + 1024;
        if (atomicAdd(sub, 1u) == 31u)
            if (atomicAdd(root, 1u) == 7u)
                for (int i = 0; i < 256; i++)
                    __hip_atomic_store(&flags[i * 16], e,
                                       __ATOMIC_RELAXED, __HIP_MEMORY_SCOPE_AGENT);
        if (wait)
            while (__hip_atomic_load(&flags[bid * 16],
                                     __ATOMIC_RELAXED, __HIP_MEMORY_SCOPE_AGENT) < e)
                __builtin_amdgcn_s_sleep(1);
    }
    __syncthreads();
}

// ---------------------------------------------------------------------------
// MLP layer (r0-proven mapping): 256 blocks = 128 f-cols x 2 graph-halves.
// vin/stats via agent loads; vout via agent store; stats out via spread
// atomicAdd (2-way contention per line).
// ---------------------------------------------------------------------------
__device__ void mlp_phase(float* u,
    const float* __restrict__ vin, const float* __restrict__ statsin,
    const float* __restrict__ gbn, const float* __restrict__ bbn,
    const float* __restrict__ W, const float* __restrict__ bias,
    float* __restrict__ vout, float* __restrict__ statsout)
{
    float* scale_s = u;          // 128
    float* shift_s = u + 128;    // 128
    float* wcol    = u + 256;    // 128
    float* pc      = u + 384;    // 256
    float* h_s     = u + 640;    // 64*129
    const int b = blockIdx.x, t = threadIdx.x;
    const int f = b & 127, gh = b >> 7;
    if (t < 128) {
        float s1 = lda(&statsin[t * 2]), s2 = lda(&statsin[t * 2 + 1]);
        float m = s1 * (1.f / 128.f);
        float var = s2 * (1.f / 128.f) - m * m;
        float sc = gbn[t] * rsqrtf(var + BN_EPS);
        scale_s[t] = sc;
        shift_s[t] = bbn[t] - m * sc;
        wcol[t] = W[t * 128 + f];
    }
    __syncthreads();
    const float* vbase = vin + (size_t)gh * 64 * 128;
    {
        const int k = t & 127;                 // fixed per thread (256%128==0)
        const float sck = scale_s[k], shk = shift_s[k];
        #pragma unroll
        for (int it = 0; it < 32; ++it) {      // 8192 coalesced scalar loads
            int idx = it * 256 + t;
            int gl = idx >> 7;
            h_s[gl * 129 + k] = lda(&vbase[idx]) * sck + shk;
        }
    }
    __syncthreads();
    {
        const int gl = t & 63, kh = t >> 6;
        float acc = 0.f;
        #pragma unroll 8
        for (int k = kh * 32; k < kh * 32 + 32; ++k)
            acc += h_s[gl * 129 + k] * wcol[k];
        pc[gl * 4 + kh] = acc;
    }
    __syncthreads();
    if (t < 64) {   // wave 0
        float v = fmaxf(pc[t * 4] + pc[t * 4 + 1] + pc[t * 4 + 2] + pc[t * 4 + 3]
                        + bias[f], 0.f);
        stg(&vout[(size_t)(gh * 64 + t) * 128 + f], v);
        float s1 = v, s2 = v * v;
        #pragma unroll
        for (int off = 32; off > 0; off >>= 1) {
            s1 += __shfl_down(s1, off, 64);
            s2 += __shfl_down(s2, off, 64);
        }
        if (t == 0) {
            atomicAdd(&statsout[f * 2], s1);
            atomicAdd(&statsout[f * 2 + 1], s2);
        }
    }
}

// ---------------------------------------------------------------------------
// Fused: F (conv 128 blks + gemm 64 blks K=160 -> part) |bar| R+bn0 |bar|
// M1 |bar| M2 |bar(exit>=128)| O. All cross-phase data sc1-coherent.
// ---------------------------------------------------------------------------
__global__ __launch_bounds__(256) void k_fused(
    const float* __restrict__ x, const float* __restrict__ ew,
    const float* __restrict__ W1, const float* __restrict__ b1,
    const float* __restrict__ W2, const float* __restrict__ b2,
    const float* __restrict__ Wm0, const float* __restrict__ bm0,
    const float* __restrict__ gbn0, const float* __restrict__ bbn0,
    const float* __restrict__ Wm1, const float* __restrict__ bm1,
    const float* __restrict__ gbn1, const float* __restrict__ bbn1,
    const float* __restrict__ Wm2, const float* __restrict__ bm2,
    const float* __restrict__ gbn2, const float* __restrict__ bbn2,
    const float* __restrict__ Wo, const float* __restrict__ bo,
    float* __restrict__ ws, float* __restrict__ out)
{
    __shared__ __align__(16) float u[16128];   // 63KB union, reused per phase
    unsigned* bu = (unsigned*)ws;              // ctrl: 5120 u32 (20KB)
    float* stats = ws + 5120;                  // 768 (bn0|bn1|bn2), memset 0
    float* part  = ws + 6144;                  // 64*8192 = 524288
    float* ppart = part + 64 * 8192;           // 16384
    float* v0 = ppart + 16384;                 // 16384
    float* v1 = v0 + 16384;
    float* v2 = v1 + 16384;
    const int bid = blockIdx.x, t = threadIdx.x;

    // ======================= phase F =======================
    if (bid < 128) {
        // ---------------- conv path (one block per graph) ----------------
        float* ew_s     = u;             // [i][j] 4096 (raw)
        float* x_s      = u + 4096;      // x^T [k][i] 1024
        float* W1_s     = u + 5120;      // [k][f] 2048
        float* P_s      = u + 7168;      // [i][f] 8192 (dinv_i * P)
        float* b1_s     = u + 15360;     // 128
        float* dinv_s   = u + 15488;     // 64
        float* t_s      = u + 15552;     // 64
        float* zp       = u + 4096;      // overlay (x_s/W1_s dead): 16*132
        float* z_full   = u + 15616;     // 128
        float* pooled_s = u + 15744;     // 128
        float* pp2      = u + 15872;     // 256
        const int g = bid;
        {
            const float4* ew4 = (const float4*)(ew + g * EPG);
            float4* ews4 = (float4*)ew_s;
            #pragma unroll
            for (int i = 0; i < 4; i++) ews4[t + 256 * i] = ew4[t + 256 * i];
            const int xi = t & 63, k4 = (t >> 6) * 4;
            float4 xv = *(const float4*)(x + g * NPG * IN + xi * IN + k4);
            x_s[(k4 + 0) * 64 + xi] = xv.x;
            x_s[(k4 + 1) * 64 + xi] = xv.y;
            x_s[(k4 + 2) * 64 + xi] = xv.z;
            x_s[(k4 + 3) * 64 + xi] = xv.w;
            ((float4*)W1_s)[t]       = ((const float4*)W1)[t];
            ((float4*)W1_s)[t + 256] = ((const float4*)W1)[t + 256];
            if (t < 128) b1_s[t] = b1[t];
        }
        __syncthreads();

        if (t < NPG) {
            float s = 0.f;
            #pragma unroll 8
            for (int i = 0; i < NPG; i++) s += ew_s[i * NPG + t];
            dinv_s[t] = (s > 0.f) ? rsqrtf(s) : 0.f;
        }
        __syncthreads();

        {   // t_s[i] = dinv_i * (sum_j ew[i,j] dinv_j) / 64
            const int j = t & 63, q = t >> 6;
            const float dj = dinv_s[j];
            for (int i = q * 16; i < q * 16 + 16; i++) {
                float vv = ew_s[i * NPG + j] * dj;
                #pragma unroll
                for (int off = 32; off > 0; off >>= 1) vv += __shfl_down(vv, off, 64);
                if (j == 0) t_s[i] = dinv_s[i] * vv * (1.f / 64.f);
            }
        }

        {   // P' = dinv_i * (x @ W1)
            const int it = t & 15, ft = t >> 4;
            const int i0 = it * 4, f0 = ft * 8;
            float accp[4][8];
            #pragma unroll
            for (int a = 0; a < 4; a++)
                #pragma unroll
                for (int c = 0; c < 8; c++) accp[a][c] = 0.f;
            #pragma unroll
            for (int k = 0; k < IN; k++) {
                const float4 a4  = *(const float4*)(x_s + k * 64 + i0);
                const float4 b0v = *(const float4*)(W1_s + k * DM + f0);
                const float4 b1v = *(const float4*)(W1_s + k * DM + f0 + 4);
                const float av[4] = {a4.x, a4.y, a4.z, a4.w};
                const float bv[8] = {b0v.x, b0v.y, b0v.z, b0v.w, b1v.x, b1v.y, b1v.z, b1v.w};
                #pragma unroll
                for (int a = 0; a < 4; a++)
                    #pragma unroll
                    for (int c = 0; c < 8; c++) accp[a][c] += av[a] * bv[c];
            }
            #pragma unroll
            for (int a = 0; a < 4; a++) {
                const float di = dinv_s[i0 + a];
                float4* o = (float4*)(P_s + (i0 + a) * DM + f0);
                o[0] = make_float4(di * accp[a][0], di * accp[a][1],
                                   di * accp[a][2], di * accp[a][3]);
                o[1] = make_float4(di * accp[a][4], di * accp[a][5],
                                   di * accp[a][6], di * accp[a][7]);
            }
        }
        __syncthreads();

        {   // aggregation + z-partials
            const int jt = t & 15, ft = t >> 4;
            const int j0 = jt * 4, f0 = ft * 8;
            float acc[4][8];
            #pragma unroll
            for (int a = 0; a < 4; a++)
                #pragma unroll
                for (int c = 0; c < 8; c++) acc[a][c] = 0.f;
            #pragma unroll 4
            for (int k = 0; k < 64; k++) {
                const float4 a4  = *(const float4*)(ew_s + k * 64 + j0);
                const float4 b0v = *(const float4*)(P_s + k * DM + f0);
                const float4 b1v = *(const float4*)(P_s + k * DM + f0 + 4);
                const float av[4] = {a4.x, a4.y, a4.z, a4.w};
                const float bv[8] = {b0v.x, b0v.y, b0v.z, b0v.w, b1v.x, b1v.y, b1v.z, b1v.w};
                #pragma unroll
                for (int a = 0; a < 4; a++)
                    #pragma unroll
                    for (int c = 0; c < 8; c++) acc[a][c] += av[a] * bv[c];
            }
            float zpart[8];
            #pragma unroll
            for (int c = 0; c < 8; c++) zpart[c] = 0.f;
            #pragma unroll
            for (int a = 0; a < 4; a++) {
                const float dj = dinv_s[j0 + a], tj = t_s[j0 + a];
                #pragma unroll
                for (int c = 0; c < 8; c++) {
                    float h = fmaxf(dj * acc[a][c] + b1_s[f0 + c], 0.f);
                    zpart[c] += tj * h;
                }
            }
            float4* zo = (float4*)(zp + jt * 132 + f0);
            zo[0] = make_float4(zpart[0], zpart[1], zpart[2], zpart[3]);
            zo[1] = make_float4(zpart[4], zpart[5], zpart[6], zpart[7]);
        }
        __syncthreads();

        if (t < 128) {
            float s = 0.f;
            #pragma unroll
            for (int jt = 0; jt < 16; jt++) s += zp[jt * 132 + t];
            z_full[t] = s;
        }
        __syncthreads();

        {   // pooled = relu(z @ W2 + b2)
            const int c = t & 127, kh = t >> 7;
            float acc = 0.f;
            #pragma unroll 8
            for (int k = kh * 64; k < kh * 64 + 64; k++)
                acc += z_full[k] * W2[k * DM + c];
            pp2[kh * 128 + c] = acc;
        }
        __syncthreads();
        if (t < 128) pooled_s[t] = fmaxf(pp2[t] + pp2[128 + t] + b2[t], 0.f);
        __syncthreads();

        {   // ppart = pooled @ Wm0[0:128,:]
            const int f = t & 127, kh = t >> 7;
            float acc = 0.f;
            #pragma unroll 8
            for (int k = kh * 64; k < kh * 64 + 64; k++)
                acc += pooled_s[k] * Wm0[k * DM + f];
            pp2[kh * 128 + f] = acc;
        }
        __syncthreads();
        if (t < 128) stg(&ppart[g * DM + t], pp2[t] + pp2[128 + t]);
    } else if (bid < 192) {
        // -------- gemm x/ew path: 64 blocks, K=160 (2 staging passes) --------
        const int c = bid - 128;
        const int kc = c >> 1, fh = c & 1;
        float* a_s = u;                  // [k][g] 80*132
        float* b_s = u + 10560;          // [k][fl] 80*64

        const int gthr = t & 31, fthr = t >> 5;   // 32 x 8
        const int g0 = gthr * 4, f0 = fthr * 8;
        float acc[4][8];
        #pragma unroll
        for (int i = 0; i < 4; i++)
            #pragma unroll
            for (int jx = 0; jx < 8; jx++) acc[i][jx] = 0.f;

        for (int pass = 0; pass < 2; pass++) {
            const int K0 = kc * 160 + pass * 80;
            float4 va[8], vb2[2], vc[5];
            #pragma unroll
            for (int it = 0; it < 8; it++) {             // k 0..63: 2048 float4
                int idx = it * 256 + t;
                int gg = idx >> 4, k4 = (idx & 15) << 2;
                int K = K0 + k4;
                const float* src = (K < 1024) ? (x + gg * 1024 + K)
                                              : (ew + gg * 4096 + (K - 1024));
                va[it] = *(const float4*)src;
            }
            #pragma unroll
            for (int it = 0; it < 2; it++) {             // k 64..79: 512 float4
                int idx = it * 256 + t;
                int gg = idx >> 2, k4 = 64 + ((idx & 3) << 2);
                int K = K0 + k4;
                const float* src = (K < 1024) ? (x + gg * 1024 + K)
                                              : (ew + gg * 4096 + (K - 1024));
                vb2[it] = *(const float4*)src;
            }
            #pragma unroll
            for (int it = 0; it < 5; it++) {             // Wm0 slice: 1280 float4
                int idx = it * 256 + t;
                int k = idx >> 4, fl4 = (idx & 15) << 2;
                vc[it] = *(const float4*)(Wm0 + (size_t)(128 + K0 + k) * 128
                                          + fh * 64 + fl4);
            }
            #pragma unroll
            for (int it = 0; it < 8; it++) {
                int idx = it * 256 + t;
                int gg = idx >> 4, k4 = (idx & 15) << 2;
                a_s[(k4 + 0) * 132 + gg] = fmaxf(va[it].x, 0.f);
                a_s[(k4 + 1) * 132 + gg] = fmaxf(va[it].y, 0.f);
                a_s[(k4 + 2) * 132 + gg] = fmaxf(va[it].z, 0.f);
                a_s[(k4 + 3) * 132 + gg] = fmaxf(va[it].w, 0.f);
            }
            #pragma unroll
            for (int it = 0; it < 2; it++) {
                int idx = it * 256 + t;
                int gg = idx >> 2, k4 = 64 + ((idx & 3) << 2);
                a_s[(k4 + 0) * 132 + gg] = fmaxf(vb2[it].x, 0.f);
                a_s[(k4 + 1) * 132 + gg] = fmaxf(vb2[it].y, 0.f);
                a_s[(k4 + 2) * 132 + gg] = fmaxf(vb2[it].z, 0.f);
                a_s[(k4 + 3) * 132 + gg] = fmaxf(vb2[it].w, 0.f);
            }
            #pragma unroll
            for (int it = 0; it < 5; it++) {
                int idx = it * 256 + t;
                int k = idx >> 4, fl4 = (idx & 15) << 2;
                *(float4*)(b_s + k * 64 + fl4) = vc[it];
            }
            __syncthreads();

            #pragma unroll 4
            for (int k = 0; k < 80; k++) {
                const float4 a4  = *(const float4*)(a_s + k * 132 + g0);
                const float4 c0v = *(const float4*)(b_s + k * 64 + f0);
                const float4 c1v = *(const float4*)(b_s + k * 64 + f0 + 4);
                const float av[4] = {a4.x, a4.y, a4.z, a4.w};
                const float bv[8] = {c0v.x, c0v.y, c0v.z, c0v.w, c1v.x, c1v.y, c1v.z, c1v.w};
                #pragma unroll
                for (int i = 0; i < 4; i++)
                    #pragma unroll
                    for (int jx = 0; jx < 8; jx++) acc[i][jx] += av[i] * bv[jx];
            }
            __syncthreads();   // before restage of pass 1
        }

        float* pp = part + (size_t)c * 8192;   // [g][fl] 128x64, sc1 stores
        #pragma unroll
        for (int i = 0; i < 4; i++) {
            const int base = (g0 + i) * 64 + f0;
            #pragma unroll
            for (int jx = 0; jx < 8; jx++) stg(&pp[base + jx], acc[i][jx]);
        }
    }
    // blocks 192..255 idle in F, arrive immediately
    gbar(bu, 1u, bid, t, true);

    // ============ phase R: reduce part + bn0 (32 gt x 8 fgrp) ============
    {
        float* r1  = u;          // 1024
        float* sv  = u + 1024;   // 64
        float* sv2 = u + 1088;   // 64
        const int fgrp = bid & 7, gt = bid >> 3;
        const int f4 = t & 3, gl = (t >> 2) & 3, ch = t >> 4;   // ch 0..15
        const int g = gt * 4 + gl;
        const int fbase = fgrp * 16 + f4 * 4;
        const int fh = fbase >> 6, fl = fbase & 63;
        // thread sums 2 k-chunks: kc = ch and ch+16
        float r0v = 0.f, r1v = 0.f, r2v = 0.f, r3v = 0.f;
        #pragma unroll
        for (int q = 0; q < 2; q++) {
            const int kc = ch + q * 16;
            const float* p = part + (size_t)(kc * 2 + fh) * 8192 + g * 64 + fl;
            r0v += lda(&p[0]); r1v += lda(&p[1]);
            r2v += lda(&p[2]); r3v += lda(&p[3]);
        }
        float* r = r1 + ch * 64 + gl * 16 + f4 * 4;
        r[0] = r0v; r[1] = r1v; r[2] = r2v; r[3] = r3v;
        __syncthreads();

        if (t < 64) {
            const int fsub = t & 15, gl2 = t >> 4;
            const int f = fgrp * 16 + fsub, gg = gt * 4 + gl2;
            float s = bm0[f] + lda(&ppart[gg * DM + f]);
            #pragma unroll
            for (int c2 = 0; c2 < 16; c2++) s += r1[c2 * 64 + gl2 * 16 + fsub];
            s = fmaxf(s, 0.f);
            stg(&v0[gg * DM + f], s);
            sv[t] = s; sv2[t] = s * s;
        }
        __syncthreads();
        if (t < 16) {
            float s1 = sv[t] + sv[t + 16] + sv[t + 32] + sv[t + 48];
            float s2 = sv2[t] + sv2[t + 16] + sv2[t + 32] + sv2[t + 48];
            atomicAdd(&stats[(fgrp * 16 + t) * 2], s1);
            atomicAdd(&stats[(fgrp * 16 + t) * 2 + 1], s2);
        }
    }
    gbar(bu, 2u, bid, t, true);

    // ======================= phases M1, M2 =======================
    mlp_phase(u, v0, stats,       gbn0, bbn0, Wm1, bm1, v1, stats + 256);
    gbar(bu, 3u, bid, t, true);
    mlp_phase(u, v1, stats + 256, gbn1, bbn1, Wm2, bm2, v2, stats + 512);
    gbar(bu, 4u, bid, t, bid < 128);   // blocks >=128 arrive and exit
    if (bid >= 128) return;

    // ============ phase O: BN2 + output (128 blocks x 1 graph) ============
    {
        float* Wo_s = u;            // 8192 (32KB)
        float* vrow = u + 8192;     // 128
        float* sc   = u + 8320;     // 128
        float* sh   = u + 8448;     // 128
        float* pc   = u + 8576;     // 256
        const float* st2 = stats + 512;
        const int g = bid;
        if (t < 128) {
            float s1 = lda(&st2[t * 2]), s2 = lda(&st2[t * 2 + 1]);
            float m = s1 * (1.f / 128.f);
            float var = s2 * (1.f / 128.f) - m * m;
            float scv = gbn2[t] * rsqrtf(var + BN_EPS);
            sc[t] = scv;
            sh[t] = bbn2[t] - m * scv;
        }
        {   // stage Wo 128x64 (2048 float4)
            const float4* wo4 = (const float4*)Wo;
            float4* wos4 = (float4*)Wo_s;
            #pragma unroll
            for (int it = 0; it < 8; it++) wos4[it * 256 + t] = wo4[it * 256 + t];
        }
        __syncthreads();
        if (t < 128) vrow[t] = lda(&v2[(size_t)g * 128 + t]) * sc[t] + sh[t];
        __syncthreads();
        {   // 64 o-cols x 4 k-quarters
            const int o = t & 63, kh = t >> 6;
            float acc = 0.f;
            #pragma unroll 8
            for (int k = kh * 32; k < kh * 32 + 32; k++)
                acc += vrow[k] * Wo_s[k * 64 + o];
            pc[kh * 64 + o] = acc;
        }
        __syncthreads();
        if (t < 64)
            out[g * NOUT + t] = pc[t] + pc[64 + t] + pc[128 + t] + pc[192 + t] + bo[t];
    }
}

extern "C" void kernel_launch(void* const* d_in, const int* in_sizes, int n_in,
                              void* d_out, int out_size, void* d_ws, size_t ws_size,
                              hipStream_t stream)
{
    const float* x   = (const float*)d_in[0];
    const float* ew  = (const float*)d_in[2];
    const float* W1  = (const float*)d_in[4];
    const float* b1  = (const float*)d_in[5];
    const float* W2  = (const float*)d_in[6];
    const float* b2  = (const float*)d_in[7];
    const float* Wm0 = (const float*)d_in[8];
    const float* bm0 = (const float*)d_in[9];
    const float* g0  = (const float*)d_in[10];
    const float* be0 = (const float*)d_in[11];
    const float* Wm1 = (const float*)d_in[12];
    const float* bm1 = (const float*)d_in[13];
    const float* g1  = (const float*)d_in[14];
    const float* be1 = (const float*)d_in[15];
    const float* Wm2 = (const float*)d_in[16];
    const float* bm2 = (const float*)d_in[17];
    const float* g2  = (const float*)d_in[18];
    const float* be2 = (const float*)d_in[19];
    const float* Wo  = (const float*)d_in[20];
    const float* bo  = (const float*)d_in[21];

    float* ws = (float*)d_ws;
    // zero barrier ctrl (20KB) + stats (3KB): first 24576 bytes
    hipMemsetAsync(d_ws, 0, 24576, stream);
    k_fused<<<256, 256, 0, stream>>>(x, ew, W1, b1, W2, b2,
                                     Wm0, bm0, g0, be0,
                                     Wm1, bm1, g1, be1,
                                     Wm2, bm2, g2, be2,
                                     Wo, bo, ws, (float*)d_out);
}